// Round 1
// baseline (115.746 us; speedup 1.0000x reference)
//
#include <hip/hip_runtime.h>
#include <math.h>

// Problem constants
#define NB    32      // batch
#define CC    1024    // channels
#define LL    16      // tokens
#define NHEAD 16
#define GS    64      // group size == head dim
#define HW    1024    // 32*32 spatial
#define CX    128     // spatial chunk
#define NCHUNK (HW / CX)

// ---------------------------------------------------------------------------
// Kernel 1: query = Wq @ token + bq   ([1024,1024] @ [1024,16] per n)
// grid (16 o-blocks, 32 n), 256 threads.
// ---------------------------------------------------------------------------
__global__ __launch_bounds__(256) void query_kernel(
        const float* __restrict__ Wq, const float* __restrict__ bq,
        const float* __restrict__ token, float* __restrict__ q_ws) {
    __shared__ float wq_lds[64 * 65];   // [c_local][o], pad 65 -> conflict-free
    __shared__ float tok_lds[64 * 16];  // [c_local][l]

    const int t  = threadIdx.x;
    const int ob = blockIdx.x;
    const int n  = blockIdx.y;

    const int o_c = t & 63;     // compute role: output channel within block
    const int lq  = t >> 6;     // l-quad (wave id)
    float acc0 = 0.f, acc1 = 0.f, acc2 = 0.f, acc3 = 0.f;

    for (int cb = 0; cb < 16; ++cb) {
        __syncthreads();  // protect LDS from previous iter's readers
        // stage Wq tile transposed: wq_lds[c][o]
        {
            const int c4 = t & 15, o0 = t >> 4;
#pragma unroll
            for (int k = 0; k < 4; ++k) {
                const int o = o0 + 16 * k;
                const float4 v = *(const float4*)(Wq + (size_t)(ob * 64 + o) * 1024 + cb * 64 + c4 * 4);
                wq_lds[(c4 * 4 + 0) * 65 + o] = v.x;
                wq_lds[(c4 * 4 + 1) * 65 + o] = v.y;
                wq_lds[(c4 * 4 + 2) * 65 + o] = v.z;
                wq_lds[(c4 * 4 + 3) * 65 + o] = v.w;
            }
        }
        // stage token tile: tok_lds[c][l]
        {
            const int cl = t >> 2, l4 = t & 3;
            const float4 v = *(const float4*)(token + (size_t)n * 16384 + (size_t)(cb * 64 + cl) * 16 + l4 * 4);
            *(float4*)(tok_lds + cl * 16 + l4 * 4) = v;
        }
        __syncthreads();
#pragma unroll 8
        for (int ci = 0; ci < 64; ++ci) {
            const float  w  = wq_lds[ci * 65 + o_c];
            const float4 tv = *(const float4*)(tok_lds + ci * 16 + lq * 4);
            acc0 += w * tv.x; acc1 += w * tv.y; acc2 += w * tv.z; acc3 += w * tv.w;
        }
    }
    const float b = bq[ob * 64 + o_c];
    float4 r; r.x = acc0 + b; r.y = acc1 + b; r.z = acc2 + b; r.w = acc3 + b;
    *(float4*)(q_ws + (size_t)n * 16384 + (size_t)(ob * 64 + o_c) * 16 + lq * 4) = r;
}

// ---------------------------------------------------------------------------
// Kernel 2: fused  feature-copy + key/value-free attention.
//   s[x,l]   = f^T (Wk^T q / 8)          (bk drops: constant along softmax axis)
//   coef     = softmax_x(s)
//   tok[d,l] = Wv @ (f @ coef) + bv      (softmax rows sum to 1)
// One block per (n, head). 256 threads = 4 waves.
// ---------------------------------------------------------------------------
__global__ __launch_bounds__(256) void attn_kernel(
        const float* __restrict__ feat, const float* __restrict__ q_ws,
        const float* __restrict__ Wk, const float* __restrict__ Wv,
        const float* __restrict__ bv,
        float* __restrict__ out0, float* __restrict__ out1) {
    __shared__ float f_lds[CX * 65];     // [x][i], pad 65: conflict-free both phases (33.3 KB)
    __shared__ float s_lds[CX * 20];     // [x][l], pad 20: aligned float4 rows (10.2 KB)
    __shared__ float qk_lds[64 * 16];    // [i][l]
    __shared__ float scale_lds[16];
    __shared__ float z_lds[16];

    const int t   = threadIdx.x;
    const int bid = blockIdx.x;
    const int n   = bid >> 4;
    const int h   = bid & 15;

    // --- load q slice [64][16] into s_lds (aliased; s_lds unused yet) ---
    ((float4*)s_lds)[t] = ((const float4*)(q_ws + (size_t)n * 16384 + (size_t)h * 1024))[t];
    __syncthreads();

    // --- qk[i][l] = (1/8) * sum_d Wk[h][d][i] * q[d][l] ---
    {
        const int i = t & 63, lq = t >> 6;
        float a0 = 0.f, a1 = 0.f, a2 = 0.f, a3 = 0.f;
#pragma unroll 8
        for (int d = 0; d < 64; ++d) {
            const float  wk = Wk[(size_t)h * 4096 + d * 64 + i];     // coalesced over i
            const float4 q4 = *(const float4*)(s_lds + d * 16 + lq * 4);
            a0 += wk * q4.x; a1 += wk * q4.y; a2 += wk * q4.z; a3 += wk * q4.w;
        }
        float4 r; r.x = a0 * 0.125f; r.y = a1 * 0.125f; r.z = a2 * 0.125f; r.w = a3 * 0.125f;
        *(float4*)(qk_lds + i * 16 + lq * 4) = r;
    }

    // roles
    const int sm_l = t >> 4, sm_r = t & 15;   // softmax: 16-lane group per l (intra-wave)
    const int fc_i = t & 63, fc_lq = t >> 6;  // fc / epilogue
    const int sx   = t & 127, slh = t >> 7;   // logits: x, l-half

    float m_run = -INFINITY, Z_run = 0.f;
    float fc0 = 0.f, fc1 = 0.f, fc2 = 0.f, fc3 = 0.f;

    const size_t fbase = (size_t)n * 1048576 + (size_t)h * 65536;
    __syncthreads();  // qk_lds + s_lds handoff

    for (int ch = 0; ch < NCHUNK; ++ch) {
        const int x0 = ch * CX;
        // --- stage f chunk [64][CX] -> f_lds[x][i] (transposed), fused out0 copy ---
        {
            const int x4 = t & 31, i0 = t >> 5;
#pragma unroll
            for (int r8 = 0; r8 < 8; ++r8) {
                const int i = i0 + 8 * r8;
                const size_t g = fbase + (size_t)i * 1024 + x0 + x4 * 4;
                const float4 v = *(const float4*)(feat + g);
                *(float4*)(out0 + g) = v;                 // passthrough copy
                f_lds[(x4 * 4 + 0) * 65 + i] = v.x;
                f_lds[(x4 * 4 + 1) * 65 + i] = v.y;
                f_lds[(x4 * 4 + 2) * 65 + i] = v.z;
                f_lds[(x4 * 4 + 3) * 65 + i] = v.w;
            }
        }
        __syncthreads();
        // --- logits: s[x][l] = sum_i f[x][i] * qk[i][l], 8 l's per thread ---
        {
            float s0=0,s1=0,s2=0,s3=0,s4=0,s5=0,s6=0,s7=0;
#pragma unroll 8
            for (int i = 0; i < 64; ++i) {
                const float  fv = f_lds[sx * 65 + i];
                const float4 qa = *(const float4*)(qk_lds + i * 16 + slh * 8);
                const float4 qb = *(const float4*)(qk_lds + i * 16 + slh * 8 + 4);
                s0 += fv * qa.x; s1 += fv * qa.y; s2 += fv * qa.z; s3 += fv * qa.w;
                s4 += fv * qb.x; s5 += fv * qb.y; s6 += fv * qb.z; s7 += fv * qb.w;
            }
            *(float4*)(s_lds + sx * 20 + slh * 8)     = make_float4(s0, s1, s2, s3);
            *(float4*)(s_lds + sx * 20 + slh * 8 + 4) = make_float4(s4, s5, s6, s7);
        }
        __syncthreads();
        // --- online softmax over this chunk (group of 16 lanes per l) ---
        {
            float v[8];
            float cmax = -INFINITY;
#pragma unroll
            for (int j = 0; j < 8; ++j) {
                v[j] = s_lds[(sm_r + 16 * j) * 20 + sm_l];
                cmax = fmaxf(cmax, v[j]);
            }
#pragma unroll
            for (int msk = 8; msk >= 1; msk >>= 1)
                cmax = fmaxf(cmax, __shfl_xor(cmax, msk));
            const float m_new = fmaxf(m_run, cmax);
            const float rs = __expf(m_run - m_new);   // first chunk: exp(-inf)=0
            float lsum = 0.f;
#pragma unroll
            for (int j = 0; j < 8; ++j) {
                const float p = __expf(v[j] - m_new);
                s_lds[(sm_r + 16 * j) * 20 + sm_l] = p;
                lsum += p;
            }
#pragma unroll
            for (int msk = 8; msk >= 1; msk >>= 1)
                lsum += __shfl_xor(lsum, msk);
            Z_run = Z_run * rs + lsum;
            m_run = m_new;
            if (sm_r == 0) scale_lds[sm_l] = rs;
        }
        __syncthreads();
        // --- fc[i][l] accumulate: rescale then += sum_x f[x][i] * p[x][l] ---
        {
            const float4 rs4 = *(const float4*)(scale_lds + fc_lq * 4);
            fc0 *= rs4.x; fc1 *= rs4.y; fc2 *= rs4.z; fc3 *= rs4.w;
#pragma unroll 8
            for (int x = 0; x < CX; ++x) {
                const float  fv = f_lds[x * 65 + fc_i];
                const float4 p4 = *(const float4*)(s_lds + x * 20 + fc_lq * 4);
                fc0 += fv * p4.x; fc1 += fv * p4.y; fc2 += fv * p4.z; fc3 += fv * p4.w;
            }
        }
        __syncthreads();
    }

    // --- finalize: stage Wv transposed into f_lds (free now), publish Z ---
    if (sm_r == 0) z_lds[sm_l] = Z_run;
    {
#pragma unroll
        for (int k = 0; k < 4; ++k) {
            const int flat4 = t + 256 * k;
            const int d = flat4 >> 4, i4 = flat4 & 15;
            const float4 v = *(const float4*)(Wv + (size_t)h * 4096 + d * 64 + i4 * 4);
            f_lds[(i4 * 4 + 0) * 65 + d] = v.x;   // wv_lds[i][d]
            f_lds[(i4 * 4 + 1) * 65 + d] = v.y;
            f_lds[(i4 * 4 + 2) * 65 + d] = v.z;
            f_lds[(i4 * 4 + 3) * 65 + d] = v.w;
        }
    }
    __syncthreads();
    // normalize fc by Z, park in s_lds[i][l]
    {
        const float4 z4 = *(const float4*)(z_lds + fc_lq * 4);
        float4 r; r.x = fc0 / z4.x; r.y = fc1 / z4.y; r.z = fc2 / z4.z; r.w = fc3 / z4.w;
        *(float4*)(s_lds + fc_i * 20 + fc_lq * 4) = r;
    }
    __syncthreads();
    // tok[d][l] = sum_i Wv[d][i] * fcn[i][l] + bv[h*64+d]
    {
        const int d = fc_i, lq = fc_lq;
        float a0 = 0.f, a1 = 0.f, a2 = 0.f, a3 = 0.f;
#pragma unroll 8
        for (int i = 0; i < 64; ++i) {
            const float  wv = f_lds[i * 65 + d];
            const float4 f4 = *(const float4*)(s_lds + i * 20 + lq * 4);
            a0 += wv * f4.x; a1 += wv * f4.y; a2 += wv * f4.z; a3 += wv * f4.w;
        }
        const float b = bv[h * 64 + d];
        float4 r; r.x = a0 + b; r.y = a1 + b; r.z = a2 + b; r.w = a3 + b;
        *(float4*)(out1 + (size_t)n * 16384 + (size_t)(h * 64 + d) * 16 + lq * 4) = r;
    }
}

// ---------------------------------------------------------------------------
extern "C" void kernel_launch(void* const* d_in, const int* in_sizes, int n_in,
                              void* d_out, int out_size, void* d_ws, size_t ws_size,
                              hipStream_t stream) {
    const float* feature = (const float*)d_in[0];
    const float* token   = (const float*)d_in[1];
    const float* Wq      = (const float*)d_in[2];
    const float* bq      = (const float*)d_in[3];
    const float* Wk      = (const float*)d_in[4];
    // d_in[5] = bk: provably unused (constant along softmax axis)
    const float* Wv      = (const float*)d_in[6];
    const float* bv      = (const float*)d_in[7];

    float* out0 = (float*)d_out;                       // feature passthrough
    float* out1 = out0 + (size_t)NB * CC * HW;         // tok [n][c][l]
    float* q_ws = (float*)d_ws;                        // query [32][1024][16] fp32 (2 MB)

    query_kernel<<<dim3(16, NB), 256, 0, stream>>>(Wq, bq, token, q_ws);
    attn_kernel<<<dim3(NB * NHEAD), 256, 0, stream>>>(feature, q_ws, Wk, Wv, bv, out0, out1);
}

// Round 2
// 110.886 us; speedup vs baseline: 1.0438x; 1.0438x over previous
//
#include <hip/hip_runtime.h>
#include <math.h>

// Problem constants
#define NB    32      // batch
#define CC    1024    // channels
#define LL    16      // tokens
#define NHEAD 16
#define HW    1024    // 32*32 spatial
#define SPLIT 8       // spatial splits for attn
#define CX    (HW / SPLIT)   // 128 positions per split
#define KP    4       // split-K parts for the query GEMM

typedef float f32x4 __attribute__((ext_vector_type(4)));

// ---------------------------------------------------------------------------
// Kernel 1: query partials  qp[kp][n][o][l] = Wq[o, kp-slice] @ token  (no bias)
// grid (16 ob, 32 n, 4 kp) = 2048 blocks, 4 K-iterations each.
// ---------------------------------------------------------------------------
__global__ __launch_bounds__(256) void query_partial(
        const float* __restrict__ Wq, const float* __restrict__ token,
        float* __restrict__ qp_ws) {
    __shared__ float wq_lds[64 * 65];   // [c_local][o], pad 65
    __shared__ float tok_lds[64 * 16];  // [c_local][l]

    const int t  = threadIdx.x;
    const int ob = blockIdx.x;
    const int n  = blockIdx.y;
    const int kp = blockIdx.z;

    const int o_c = t & 63;
    const int lq  = t >> 6;
    float a0 = 0.f, a1 = 0.f, a2 = 0.f, a3 = 0.f;

    for (int cb = kp * 4; cb < kp * 4 + 4; ++cb) {
        __syncthreads();
        {   // Wq tile transposed: wq_lds[c][o]
            const int c4 = (t & 15) * 4, o0 = t >> 4;
#pragma unroll
            for (int k = 0; k < 4; ++k) {
                const int o = o0 + 16 * k;
                const f32x4 v = *(const f32x4*)(Wq + (size_t)(ob * 64 + o) * 1024 + cb * 64 + c4);
                wq_lds[(c4 + 0) * 65 + o] = v[0];
                wq_lds[(c4 + 1) * 65 + o] = v[1];
                wq_lds[(c4 + 2) * 65 + o] = v[2];
                wq_lds[(c4 + 3) * 65 + o] = v[3];
            }
        }
        {   // token tile: tok_lds[c][l]
            const int cl = t >> 2, l4 = (t & 3) * 4;
            *(f32x4*)(tok_lds + cl * 16 + l4) =
                *(const f32x4*)(token + (size_t)n * 16384 + (size_t)(cb * 64 + cl) * 16 + l4);
        }
        __syncthreads();
#pragma unroll 8
        for (int ci = 0; ci < 64; ++ci) {
            const float  w  = wq_lds[ci * 65 + o_c];
            const f32x4 tv = *(const f32x4*)(tok_lds + ci * 16 + lq * 4);
            a0 += w * tv[0]; a1 += w * tv[1]; a2 += w * tv[2]; a3 += w * tv[3];
        }
    }
    f32x4 r = {a0, a1, a2, a3};
    *(f32x4*)(qp_ws + ((size_t)(kp * NB + n) * 1024 + ob * 64 + o_c) * 16 + lq * 4) = r;
}

// ---------------------------------------------------------------------------
// Kernel 2: qk[nh][i][l] = Wk[h]^T (sum_kp qp + bq) / 8.  grid 512 blocks.
// Stored as [nh][lq][i][l4] so attn_partial loads it with one coalesced float4.
// ---------------------------------------------------------------------------
__global__ __launch_bounds__(256) void qk_kernel(
        const float* __restrict__ qp_ws, const float* __restrict__ bq,
        const float* __restrict__ Wk, float* __restrict__ qk_ws) {
    __shared__ float q_lds[64 * 16];
    const int t  = threadIdx.x;
    const int nh = blockIdx.x;
    const int n  = nh >> 4, h = nh & 15;

    {   // q[d][l] = sum of KP partials + bias
        const int d = t >> 2, l4 = (t & 3) * 4;
        f32x4 s = {0.f, 0.f, 0.f, 0.f};
#pragma unroll
        for (int kp = 0; kp < KP; ++kp) {
            const f32x4 v = *(const f32x4*)(qp_ws + ((size_t)(kp * NB + n) * 1024 + h * 64 + d) * 16 + l4);
            s[0] += v[0]; s[1] += v[1]; s[2] += v[2]; s[3] += v[3];
        }
        const float b = bq[h * 64 + d];
        s[0] += b; s[1] += b; s[2] += b; s[3] += b;
        *(f32x4*)(q_lds + d * 16 + l4) = s;
    }
    __syncthreads();
    {
        const int i = t & 63, lq = t >> 6;
        float a0 = 0.f, a1 = 0.f, a2 = 0.f, a3 = 0.f;
#pragma unroll 8
        for (int d = 0; d < 64; ++d) {
            const float wk = Wk[(size_t)h * 4096 + d * 64 + i];   // coalesced over i
            const f32x4 q4 = *(const f32x4*)(q_lds + d * 16 + lq * 4);
            a0 += wk * q4[0]; a1 += wk * q4[1]; a2 += wk * q4[2]; a3 += wk * q4[3];
        }
        f32x4 r = {a0 * 0.125f, a1 * 0.125f, a2 * 0.125f, a3 * 0.125f};
        *(f32x4*)(qk_ws + (size_t)nh * 1024 + (size_t)lq * 256 + i * 4) = r;
    }
}

// ---------------------------------------------------------------------------
// Kernel 3: attn partial — one (n,h,spatial-chunk) per block. grid (512, 8).
//   stage f chunk (fused nontemporal out0 copy) -> logits -> LOCAL softmax
//   (m_p, Z_p) -> partial fc -> ws.  No serial chunk loop: 3 barriers total.
// ---------------------------------------------------------------------------
__global__ __launch_bounds__(256) void attn_partial(
        const float* __restrict__ feat, const float* __restrict__ qk_ws,
        float* __restrict__ out0, float* __restrict__ fcp_ws,
        float* __restrict__ mz_ws) {
    __shared__ float f_lds[CX * 65];   // [x][i] transposed, pad 65 (33.3 KB)
    __shared__ float s_lds[CX * 20];   // [x][l], pad 20 (10.2 KB)
    __shared__ float qk_lds[64 * 16];  // [i][l]

    const int t    = threadIdx.x;
    const int nh   = blockIdx.x;
    const int part = blockIdx.y;
    const int n    = nh >> 4, h = nh & 15;
    const size_t fbase = (size_t)n * 1048576 + (size_t)h * 65536;
    const int x0 = part * CX;

    {   // qk -> LDS (one coalesced float4 per thread)
        const f32x4 v = *(const f32x4*)(qk_ws + (size_t)nh * 1024 + t * 4);
        *(f32x4*)(qk_lds + (t & 63) * 16 + (t >> 6) * 4) = v;
    }
    {   // stage f chunk [64 i][CX x] -> f_lds[x][i], fused passthrough copy
        const int x4 = (t & 31) * 4, i0 = t >> 5;
#pragma unroll
        for (int r8 = 0; r8 < 8; ++r8) {
            const int i = i0 + 8 * r8;
            const size_t g = fbase + (size_t)i * 1024 + x0 + x4;
            const f32x4 v = __builtin_nontemporal_load((const f32x4*)(feat + g));
            __builtin_nontemporal_store(v, (f32x4*)(out0 + g));
            f_lds[(x4 + 0) * 65 + i] = v[0];
            f_lds[(x4 + 1) * 65 + i] = v[1];
            f_lds[(x4 + 2) * 65 + i] = v[2];
            f_lds[(x4 + 3) * 65 + i] = v[3];
        }
    }
    __syncthreads();
    {   // logits s[x][l] = sum_i f[x][i] * qk[i][l]  (8 l per thread)
        const int sx = t & 127, slh = (t >> 7) * 8;
        float s0=0,s1=0,s2=0,s3=0,s4=0,s5=0,s6=0,s7=0;
#pragma unroll 8
        for (int i = 0; i < 64; ++i) {
            const float fv = f_lds[sx * 65 + i];
            const f32x4 qa = *(const f32x4*)(qk_lds + i * 16 + slh);
            const f32x4 qb = *(const f32x4*)(qk_lds + i * 16 + slh + 4);
            s0 += fv * qa[0]; s1 += fv * qa[1]; s2 += fv * qa[2]; s3 += fv * qa[3];
            s4 += fv * qb[0]; s5 += fv * qb[1]; s6 += fv * qb[2]; s7 += fv * qb[3];
        }
        f32x4 ra = {s0, s1, s2, s3}, rb = {s4, s5, s6, s7};
        *(f32x4*)(s_lds + sx * 20 + slh)     = ra;
        *(f32x4*)(s_lds + sx * 20 + slh + 4) = rb;
    }
    __syncthreads();
    {   // local softmax over this chunk: 16-lane group per l (intra-wave)
        const int sm_l = t >> 4, sm_r = t & 15;
        float v[8];
        float cmax = -INFINITY;
#pragma unroll
        for (int j = 0; j < 8; ++j) {
            v[j] = s_lds[(sm_r + 16 * j) * 20 + sm_l];
            cmax = fmaxf(cmax, v[j]);
        }
#pragma unroll
        for (int msk = 8; msk >= 1; msk >>= 1)
            cmax = fmaxf(cmax, __shfl_xor(cmax, msk));
        float lsum = 0.f;
#pragma unroll
        for (int j = 0; j < 8; ++j) {
            const float pv = __expf(v[j] - cmax);
            s_lds[(sm_r + 16 * j) * 20 + sm_l] = pv;
            lsum += pv;
        }
#pragma unroll
        for (int msk = 8; msk >= 1; msk >>= 1)
            lsum += __shfl_xor(lsum, msk);
        if (sm_r == 0) {
            mz_ws[((size_t)nh * SPLIT + part) * 32 + sm_l]      = cmax;
            mz_ws[((size_t)nh * SPLIT + part) * 32 + 16 + sm_l] = lsum;
        }
    }
    __syncthreads();
    {   // partial fc[i][l] = sum_x f[x][i] * p[x][l]
        const int fi = t & 63, flq = (t >> 6) * 4;
        float c0 = 0.f, c1 = 0.f, c2 = 0.f, c3 = 0.f;
#pragma unroll 8
        for (int x = 0; x < CX; ++x) {
            const float fv = f_lds[x * 65 + fi];
            const f32x4 p4 = *(const f32x4*)(s_lds + x * 20 + flq);
            c0 += fv * p4[0]; c1 += fv * p4[1]; c2 += fv * p4[2]; c3 += fv * p4[3];
        }
        f32x4 r = {c0, c1, c2, c3};
        __builtin_nontemporal_store(r, (f32x4*)(fcp_ws + ((size_t)nh * SPLIT + part) * 1024 + t * 4));
    }
}

// ---------------------------------------------------------------------------
// Kernel 4: combine partials + Wv epilogue. grid 512 blocks.
//   fc = sum_p e^{m_p-m} fc_p ; Z = sum_p e^{m_p-m} Z_p ; tok = Wv (fc/Z) + bv
// ---------------------------------------------------------------------------
__global__ __launch_bounds__(256) void attn_combine(
        const float* __restrict__ fcp_ws, const float* __restrict__ mz_ws,
        const float* __restrict__ Wv, const float* __restrict__ bv,
        float* __restrict__ out1) {
    __shared__ float wv_lds[64 * 65];   // [i][d], pad 65
    __shared__ float s_lds[64 * 20];    // [i][l]
    __shared__ float mz_lds[SPLIT * 32];

    const int t  = threadIdx.x;
    const int nh = blockIdx.x;
    const int n  = nh >> 4, h = nh & 15;
    const int i  = t & 63, lq = t >> 6;

    mz_lds[t] = mz_ws[(size_t)nh * SPLIT * 32 + t];
#pragma unroll
    for (int k = 0; k < 4; ++k) {   // stage Wv transposed: wv_lds[i][d]
        const int flat = t + 256 * k;
        const int d = flat >> 4, i4 = (flat & 15) * 4;
        const f32x4 v = *(const f32x4*)(Wv + (size_t)h * 4096 + d * 64 + i4);
        wv_lds[(i4 + 0) * 65 + d] = v[0];
        wv_lds[(i4 + 1) * 65 + d] = v[1];
        wv_lds[(i4 + 2) * 65 + d] = v[2];
        wv_lds[(i4 + 3) * 65 + d] = v[3];
    }
    __syncthreads();

    float mg[4];
#pragma unroll
    for (int j = 0; j < 4; ++j) {
        const int l = lq * 4 + j;
        float m = -INFINITY;
#pragma unroll
        for (int pp = 0; pp < SPLIT; ++pp) m = fmaxf(m, mz_lds[pp * 32 + l]);
        mg[j] = m;
    }
    f32x4 acc = {0.f, 0.f, 0.f, 0.f};
    float Zg[4] = {0.f, 0.f, 0.f, 0.f};
#pragma unroll
    for (int pp = 0; pp < SPLIT; ++pp) {
        const f32x4 fv = __builtin_nontemporal_load(
            (const f32x4*)(fcp_ws + ((size_t)nh * SPLIT + pp) * 1024 + t * 4));
#pragma unroll
        for (int j = 0; j < 4; ++j) {
            const int l = lq * 4 + j;
            const float w = __expf(mz_lds[pp * 32 + l] - mg[j]);
            Zg[j]  += w * mz_lds[pp * 32 + 16 + l];
            acc[j] += w * fv[j];
        }
    }
#pragma unroll
    for (int j = 0; j < 4; ++j) acc[j] /= Zg[j];
    *(f32x4*)(s_lds + i * 20 + lq * 4) = acc;
    __syncthreads();
    {   // tok[d][l] = sum_i Wv[d][i] * fcn[i][l] + bv
        const int d = i;
        float a0 = 0.f, a1 = 0.f, a2 = 0.f, a3 = 0.f;
#pragma unroll 8
        for (int ii = 0; ii < 64; ++ii) {
            const float wv = wv_lds[ii * 65 + d];
            const f32x4 f4 = *(const f32x4*)(s_lds + ii * 20 + lq * 4);
            a0 += wv * f4[0]; a1 += wv * f4[1]; a2 += wv * f4[2]; a3 += wv * f4[3];
        }
        const float b = bv[h * 64 + d];
        f32x4 r = {a0 + b, a1 + b, a2 + b, a3 + b};
        *(f32x4*)(out1 + (size_t)n * 16384 + (size_t)(h * 64 + d) * 16 + lq * 4) = r;
    }
}

// ---------------------------------------------------------------------------
extern "C" void kernel_launch(void* const* d_in, const int* in_sizes, int n_in,
                              void* d_out, int out_size, void* d_ws, size_t ws_size,
                              hipStream_t stream) {
    const float* feature = (const float*)d_in[0];
    const float* token   = (const float*)d_in[1];
    const float* Wq      = (const float*)d_in[2];
    const float* bq      = (const float*)d_in[3];
    const float* Wk      = (const float*)d_in[4];
    // d_in[5] = bk: provably unused (constant along softmax axis)
    const float* Wv      = (const float*)d_in[6];
    const float* bv      = (const float*)d_in[7];

    float* out0 = (float*)d_out;                          // feature passthrough
    float* out1 = out0 + (size_t)NB * CC * HW;            // tok [n][c][l]

    float* qp_ws  = (float*)d_ws;                                  // 8 MB
    float* qk_ws  = qp_ws  + (size_t)KP * NB * 1024 * 16;          // 2 MB
    float* fcp_ws = qk_ws  + (size_t)NB * NHEAD * 1024;            // 16 MB
    float* mz_ws  = fcp_ws + (size_t)NB * NHEAD * SPLIT * 1024;    // 0.5 MB

    query_partial<<<dim3(16, NB, KP), 256, 0, stream>>>(Wq, token, qp_ws);
    qk_kernel   <<<dim3(NB * NHEAD), 256, 0, stream>>>(qp_ws, bq, Wk, qk_ws);
    attn_partial<<<dim3(NB * NHEAD, SPLIT), 256, 0, stream>>>(feature, qk_ws, out0, fcp_ws, mz_ws);
    attn_combine<<<dim3(NB * NHEAD), 256, 0, stream>>>(fcp_ws, mz_ws, Wv, bv, out1);
}

// Round 3
// 98.876 us; speedup vs baseline: 1.1706x; 1.1215x over previous
//
#include <hip/hip_runtime.h>
#include <math.h>

// Problem constants
#define NB    32
#define NHEAD 16
#define HW    1024
#define SPLIT 8
#define CX    128   // HW / SPLIT

typedef float f32x4  __attribute__((ext_vector_type(4)));
typedef short bf16x4 __attribute__((ext_vector_type(4)));
typedef short bf16x8 __attribute__((ext_vector_type(8)));

__device__ __forceinline__ short f2bf(float f) {   // fp32 -> bf16 RNE
    union { float f; unsigned u; } c; c.f = f;
    unsigned r = c.u + 0x7FFFu + ((c.u >> 16) & 1u);
    return (short)(r >> 16);
}
// XOR bank swizzle on byte bits 4..6, keyed by row bits 1..3 (bijective within
// a >=128B row; preserves 16B alignment for b128, 8B for b64).
#define SWZ(row) ((((row) >> 1) & 7) << 4)
#define MFMA16(a, b, c) __builtin_amdgcn_mfma_f32_16x16x32_bf16(a, b, c, 0, 0, 0)

__device__ __forceinline__ bf16x8 lds_ld8(const short* base, int off) {
    return *(const bf16x8*)((const char*)base + off);
}
__device__ __forceinline__ void lds_st4(short* base, int off, bf16x4 v) {
    *(bf16x4*)((char*)base + off) = v;
}

// ---------------------------------------------------------------------------
// Kernel 0: prep — bf16 casts / transposes / bias fold.
//  blocks 0..1023 : Wq [o][c] fp32 -> bf16 (same layout, K=c contiguous)
//  blocks 1024..1055 : token [n][c][l] -> tok_t [n][l][c] bf16
//  blocks 1056..1071 : Wk [h][d][i] -> Wk_t [h][i][d] bf16 ; qkb[h][i] = (Wk^T bq)/8
// ---------------------------------------------------------------------------
__global__ __launch_bounds__(256) void prep_kernel(
        const float* __restrict__ Wq, const float* __restrict__ token,
        const float* __restrict__ Wk, const float* __restrict__ bq,
        short* __restrict__ Wq_bf, short* __restrict__ tok_t,
        short* __restrict__ Wk_t, float* __restrict__ qkb) {
    __shared__ float red[256];
    const int b = blockIdx.x, t = threadIdx.x;
    if (b < 1024) {
        const size_t idx = (size_t)b * 1024 + t * 4;
        const f32x4 v = *(const f32x4*)(Wq + idx);
        bf16x4 o; o[0]=f2bf(v[0]); o[1]=f2bf(v[1]); o[2]=f2bf(v[2]); o[3]=f2bf(v[3]);
        *(bf16x4*)(Wq_bf + idx) = o;
    } else if (b < 1056) {
        const int n = b - 1024;
        const int c0 = t * 4;
        float arr[4][16];
#pragma unroll
        for (int ci = 0; ci < 4; ++ci)
#pragma unroll
            for (int lq = 0; lq < 4; ++lq) {
                const f32x4 v = *(const f32x4*)(token + (size_t)n*16384 + (size_t)(c0+ci)*16 + lq*4);
#pragma unroll
                for (int e = 0; e < 4; ++e) arr[ci][lq*4+e] = v[e];
            }
#pragma unroll
        for (int l = 0; l < 16; ++l) {
            bf16x4 o; o[0]=f2bf(arr[0][l]); o[1]=f2bf(arr[1][l]); o[2]=f2bf(arr[2][l]); o[3]=f2bf(arr[3][l]);
            *(bf16x4*)(tok_t + (size_t)n*16384 + (size_t)l*1024 + c0) = o;
        }
    } else {
        const int h = b - 1056;
        const int i = t & 63, dq = t >> 6;
        float qs = 0.f; short wt[16];
#pragma unroll
        for (int k = 0; k < 16; ++k) {
            const int d = dq*16 + k;
            const float wv = Wk[(size_t)h*4096 + d*64 + i];
            qs += wv * bq[h*64 + d];
            wt[k] = f2bf(wv);
        }
#pragma unroll
        for (int kq = 0; kq < 4; ++kq) {
            bf16x4 o; o[0]=wt[kq*4]; o[1]=wt[kq*4+1]; o[2]=wt[kq*4+2]; o[3]=wt[kq*4+3];
            *(bf16x4*)(Wk_t + (size_t)h*4096 + i*64 + dq*16 + kq*4) = o;
        }
        red[t] = qs;
        __syncthreads();
        if (t < 64)
            qkb[h*64 + t] = (red[t] + red[t+64] + red[t+128] + red[t+192]) * 0.125f;
    }
}

// ---------------------------------------------------------------------------
// Kernel 1: fused query + qk (all-MFMA). One block per (n,h); 4 waves.
//   q[o][l]  = Wq_bf[o,:] @ token_t[n][l,:]      (K=1024, 32 MFMA/wave)
//   qk[i][l] = (Wk_t[h][i,:] @ q_ld[l,:])/8 + qkb[h][i]
//   out: qk_bf[nh][l][i] bf16 (B-frag-ready, i contiguous)
// ---------------------------------------------------------------------------
__global__ __launch_bounds__(256) void queryqk_kernel(
        const short* __restrict__ Wq_bf, const short* __restrict__ tok_t,
        const short* __restrict__ Wk_t, const float* __restrict__ qkb,
        short* __restrict__ qk_bf) {
    __shared__ short q_ld[16 * 64];   // [l][d] bf16, swizzled
    const int t = threadIdx.x, w = t >> 6, L = t & 63;
    const int lr = L & 15, hg = L >> 4;
    const int nh = blockIdx.x, n = nh >> 4, h = nh & 15;

    f32x4 acc = {0.f, 0.f, 0.f, 0.f};
    const short* aA = Wq_bf + (size_t)(h*64 + w*16 + lr) * 1024 + hg*8;
    const short* aB = tok_t + (size_t)n*16384 + (size_t)lr*1024 + hg*8;
#pragma unroll 4
    for (int ks = 0; ks < 32; ++ks) {
        const bf16x8 a = *(const bf16x8*)(aA + ks*32);
        const bf16x8 bb = *(const bf16x8*)(aB + ks*32);
        acc = MFMA16(a, bb, acc);
    }
    {   // q (no bias) -> q_ld[l][d] bf16; lane holds d = w*16 + hg*4 + r
        bf16x4 qv; qv[0]=f2bf(acc[0]); qv[1]=f2bf(acc[1]); qv[2]=f2bf(acc[2]); qv[3]=f2bf(acc[3]);
        lds_st4(q_ld, (lr*128 + w*32 + hg*8) ^ SWZ(lr), qv);
    }
    __syncthreads();
    f32x4 a2 = {0.f, 0.f, 0.f, 0.f};
#pragma unroll
    for (int ks = 0; ks < 2; ++ks) {
        const bf16x8 a = *(const bf16x8*)(Wk_t + (size_t)h*4096 + (w*16 + lr)*64 + ks*32 + hg*8);
        const bf16x8 bb = lds_ld8(q_ld, (lr*128 + ks*64 + hg*16) ^ SWZ(lr));
        a2 = MFMA16(a, bb, a2);
    }
    const int i0 = w*16 + hg*4;
    bf16x4 qk4;
#pragma unroll
    for (int r = 0; r < 4; ++r)
        qk4[r] = f2bf(a2[r] * 0.125f + qkb[h*64 + i0 + r]);
    *(bf16x4*)(qk_bf + (size_t)nh*1024 + lr*64 + i0) = qk4;
}

// ---------------------------------------------------------------------------
// Kernel 2: attn partial (MFMA). One block per (nh, part); 4 waves.
//   stage f chunk (fused fp32 passthrough copy) into f_xi[x][i] + f_ix[i][x] bf16
//   logits S = f_xi @ qk  (MFMA)  -> in-register softmax (local m,Z per part)
//   P -> p_ld[l][x] bf16 ; fc = f_ix @ P (MFMA) -> fcp_ws
// ---------------------------------------------------------------------------
__global__ __launch_bounds__(256, 4) void attn_partial(
        const float* __restrict__ feat, const short* __restrict__ qk_bf,
        float* __restrict__ out0, float* __restrict__ fcp_ws,
        float* __restrict__ mz_ws) {
    __shared__ short f_xi[CX * 64];   // [x][i] bf16, 128B rows, swizzled (16 KB)
    __shared__ short f_ix[64 * CX];   // [i][x] bf16, 256B rows, swizzled (16 KB)
    __shared__ short p_ld[16 * CX];   // [l][x] bf16, 256B rows, swizzled (4 KB)
    __shared__ float red_m[64], red_z[64];

    const int t = threadIdx.x, w = t >> 6, L = t & 63;
    const int lr = L & 15, hg = L >> 4;
    const int nh = blockIdx.x, part = blockIdx.y;
    const int n = nh >> 4, h = nh & 15;
    const size_t fbase = (size_t)n*1048576 + (size_t)h*65536 + (size_t)part*CX;

    // ---- stage: 2 tasks/thread, each = 4 rows x 4 cols, fused out0 copy ----
    const int xl0 = (t & 31) * 4;
#pragma unroll
    for (int rep = 0; rep < 2; ++rep) {
        const int i0 = ((t >> 5) + 8*rep) * 4;
        f32x4 v[4];
#pragma unroll
        for (int ii = 0; ii < 4; ++ii) {
            const size_t g = fbase + (size_t)(i0+ii)*1024 + xl0;
            v[ii] = __builtin_nontemporal_load((const f32x4*)(feat + g));
            __builtin_nontemporal_store(v[ii], (f32x4*)(out0 + g));
        }
#pragma unroll
        for (int ii = 0; ii < 4; ++ii) {   // f_ix[i][x]: 4 consecutive x
            bf16x4 bv; bv[0]=f2bf(v[ii][0]); bv[1]=f2bf(v[ii][1]); bv[2]=f2bf(v[ii][2]); bv[3]=f2bf(v[ii][3]);
            lds_st4(f_ix, ((i0+ii)*256 + xl0*2) ^ SWZ(i0+ii), bv);
        }
#pragma unroll
        for (int j = 0; j < 4; ++j) {      // f_xi[x][i]: 4 consecutive i
            bf16x4 bv; bv[0]=f2bf(v[0][j]); bv[1]=f2bf(v[1][j]); bv[2]=f2bf(v[2][j]); bv[3]=f2bf(v[3][j]);
            lds_st4(f_xi, ((xl0+j)*128 + i0*2) ^ SWZ(xl0+j), bv);
        }
    }
    // qk B-fragments straight from global (L2-hot, 2 x b128)
    const bf16x8 qb0 = *(const bf16x8*)(qk_bf + (size_t)nh*1024 + lr*64 + hg*8);
    const bf16x8 qb1 = *(const bf16x8*)(qk_bf + (size_t)nh*1024 + lr*64 + 32 + hg*8);
    __syncthreads();

    // ---- logits: wave w owns x-tiles 2w, 2w+1 ----
    f32x4 s0 = {0.f,0.f,0.f,0.f}, s1 = {0.f,0.f,0.f,0.f};
    {
        const int x0r = (2*w)*16 + lr, x1r = (2*w+1)*16 + lr;
        bf16x8 a;
        a = lds_ld8(f_xi, (x0r*128      + hg*16) ^ SWZ(x0r)); s0 = MFMA16(a, qb0, s0);
        a = lds_ld8(f_xi, (x0r*128 + 64 + hg*16) ^ SWZ(x0r)); s0 = MFMA16(a, qb1, s0);
        a = lds_ld8(f_xi, (x1r*128      + hg*16) ^ SWZ(x1r)); s1 = MFMA16(a, qb0, s1);
        a = lds_ld8(f_xi, (x1r*128 + 64 + hg*16) ^ SWZ(x1r)); s1 = MFMA16(a, qb1, s1);
    }
    // ---- softmax over this part's 128 x, per l (lane-local + shfl + LDS) ----
    float ml = fmaxf(fmaxf(fmaxf(s0[0],s0[1]), fmaxf(s0[2],s0[3])),
                     fmaxf(fmaxf(s1[0],s1[1]), fmaxf(s1[2],s1[3])));
    ml = fmaxf(ml, __shfl_xor(ml, 16));
    ml = fmaxf(ml, __shfl_xor(ml, 32));
    if (L < 16) red_m[w*16 + L] = ml;
    __syncthreads();
    const float m = fmaxf(fmaxf(red_m[lr], red_m[16+lr]),
                          fmaxf(red_m[32+lr], red_m[48+lr]));
    float p0[4], p1[4]; float zs = 0.f;
#pragma unroll
    for (int r = 0; r < 4; ++r) {
        p0[r] = __expf(s0[r] - m); p1[r] = __expf(s1[r] - m);
        zs += p0[r] + p1[r];
    }
    {   // P -> p_ld[l][x] (lane holds 4 consecutive x per tile)
        bf16x4 b0; b0[0]=f2bf(p0[0]); b0[1]=f2bf(p0[1]); b0[2]=f2bf(p0[2]); b0[3]=f2bf(p0[3]);
        bf16x4 b1; b1[0]=f2bf(p1[0]); b1[1]=f2bf(p1[1]); b1[2]=f2bf(p1[2]); b1[3]=f2bf(p1[3]);
        lds_st4(p_ld, (lr*256 + (2*w)*32   + hg*8) ^ SWZ(lr), b0);
        lds_st4(p_ld, (lr*256 + (2*w+1)*32 + hg*8) ^ SWZ(lr), b1);
    }
    zs += __shfl_xor(zs, 16);
    zs += __shfl_xor(zs, 32);
    if (L < 16) red_z[w*16 + L] = zs;
    __syncthreads();

    // ---- fc = f_ix @ P : wave w owns i-tile w, K = 128 x (4 steps) ----
    f32x4 fa = {0.f,0.f,0.f,0.f};
    const int ir = w*16 + lr;
#pragma unroll
    for (int ks = 0; ks < 4; ++ks) {
        const bf16x8 a  = lds_ld8(f_ix, (ir*256 + ks*64 + hg*16) ^ SWZ(ir));
        const bf16x8 bb = lds_ld8(p_ld, (lr*256 + ks*64 + hg*16) ^ SWZ(lr));
        fa = MFMA16(a, bb, fa);
    }
    const size_t ob = ((size_t)nh*SPLIT + part) * 1024;
    const int id0 = w*16 + hg*4;
#pragma unroll
    for (int r = 0; r < 4; ++r)
        fcp_ws[ob + (size_t)(id0 + r)*16 + lr] = fa[r];
    if (w == 0 && L < 16) {
        const float Z = red_z[L] + red_z[16+L] + red_z[32+L] + red_z[48+L];
        mz_ws[((size_t)nh*SPLIT + part)*32 + L]      = m;   // lane L has l = L
        mz_ws[((size_t)nh*SPLIT + part)*32 + 16 + L] = Z;
    }
}

// ---------------------------------------------------------------------------
// Kernel 3: combine partials + Wv epilogue (unchanged, fp32). grid 512.
// ---------------------------------------------------------------------------
__global__ __launch_bounds__(256) void attn_combine(
        const float* __restrict__ fcp_ws, const float* __restrict__ mz_ws,
        const float* __restrict__ Wv, const float* __restrict__ bv,
        float* __restrict__ out1) {
    __shared__ float wv_lds[64 * 65];
    __shared__ float s_lds[64 * 20];
    __shared__ float mz_lds[SPLIT * 32];

    const int t  = threadIdx.x;
    const int nh = blockIdx.x;
    const int n  = nh >> 4, h = nh & 15;
    const int i  = t & 63, lq = t >> 6;

    mz_lds[t] = mz_ws[(size_t)nh * SPLIT * 32 + t];
#pragma unroll
    for (int k = 0; k < 4; ++k) {
        const int flat = t + 256 * k;
        const int d = flat >> 4, i4 = (flat & 15) * 4;
        const f32x4 v = *(const f32x4*)(Wv + (size_t)h * 4096 + d * 64 + i4);
        wv_lds[(i4 + 0) * 65 + d] = v[0];
        wv_lds[(i4 + 1) * 65 + d] = v[1];
        wv_lds[(i4 + 2) * 65 + d] = v[2];
        wv_lds[(i4 + 3) * 65 + d] = v[3];
    }
    __syncthreads();

    float mg[4];
#pragma unroll
    for (int j = 0; j < 4; ++j) {
        const int l = lq * 4 + j;
        float m = -INFINITY;
#pragma unroll
        for (int pp = 0; pp < SPLIT; ++pp) m = fmaxf(m, mz_lds[pp * 32 + l]);
        mg[j] = m;
    }
    f32x4 acc = {0.f, 0.f, 0.f, 0.f};
    float Zg[4] = {0.f, 0.f, 0.f, 0.f};
#pragma unroll
    for (int pp = 0; pp < SPLIT; ++pp) {
        const f32x4 fv = __builtin_nontemporal_load(
            (const f32x4*)(fcp_ws + ((size_t)nh * SPLIT + pp) * 1024 + t * 4));
#pragma unroll
        for (int j = 0; j < 4; ++j) {
            const int l = lq * 4 + j;
            const float wgt = __expf(mz_lds[pp * 32 + l] - mg[j]);
            Zg[j]  += wgt * mz_lds[pp * 32 + 16 + l];
            acc[j] += wgt * fv[j];
        }
    }
#pragma unroll
    for (int j = 0; j < 4; ++j) acc[j] /= Zg[j];
    *(f32x4*)(s_lds + i * 20 + lq * 4) = acc;
    __syncthreads();
    {
        const int d = i;
        float a0 = 0.f, a1 = 0.f, a2 = 0.f, a3 = 0.f;
#pragma unroll 8
        for (int ii = 0; ii < 64; ++ii) {
            const float wv = wv_lds[ii * 65 + d];
            const f32x4 f4 = *(const f32x4*)(s_lds + ii * 20 + lq * 4);
            a0 += wv * f4[0]; a1 += wv * f4[1]; a2 += wv * f4[2]; a3 += wv * f4[3];
        }
        const float b = bv[h * 64 + d];
        f32x4 r = {a0 + b, a1 + b, a2 + b, a3 + b};
        *(f32x4*)(out1 + (size_t)n * 16384 + (size_t)(h * 64 + d) * 16 + lq * 4) = r;
    }
}

// ---------------------------------------------------------------------------
extern "C" void kernel_launch(void* const* d_in, const int* in_sizes, int n_in,
                              void* d_out, int out_size, void* d_ws, size_t ws_size,
                              hipStream_t stream) {
    const float* feature = (const float*)d_in[0];
    const float* token   = (const float*)d_in[1];
    const float* Wq      = (const float*)d_in[2];
    const float* bq      = (const float*)d_in[3];
    const float* Wk      = (const float*)d_in[4];
    // d_in[5] = bk: provably unused (constant along softmax axis)
    const float* Wv      = (const float*)d_in[6];
    const float* bv      = (const float*)d_in[7];

    float* out0 = (float*)d_out;                      // feature passthrough
    float* out1 = out0 + (size_t)NB * 1024 * HW;      // tok [n][c][l]

    short* Wq_bf = (short*)d_ws;                               // 2 MB
    short* tok_t = Wq_bf + (size_t)1024 * 1024;                // 1 MB
    short* Wk_t  = tok_t + (size_t)NB * 16 * 1024;             // 128 KB
    short* qk_bf = Wk_t + (size_t)NHEAD * 64 * 64;             // 1 MB
    float* qkb   = (float*)(qk_bf + (size_t)NB * NHEAD * 1024);// 4 KB
    float* fcp   = qkb + NHEAD * 64;                           // 16 MB
    float* mz    = fcp + (size_t)NB * NHEAD * SPLIT * 1024;    // 0.5 MB

    prep_kernel   <<<dim3(1072), 256, 0, stream>>>(Wq, token, Wk, bq, Wq_bf, tok_t, Wk_t, qkb);
    queryqk_kernel<<<dim3(NB * NHEAD), 256, 0, stream>>>(Wq_bf, tok_t, Wk_t, qkb, qk_bf);
    attn_partial  <<<dim3(NB * NHEAD, SPLIT), 256, 0, stream>>>(feature, qk_bf, out0, fcp, mz);
    attn_combine  <<<dim3(NB * NHEAD), 256, 0, stream>>>(fcp, mz, Wv, bv, out1);
}

// Round 4
// 83.359 us; speedup vs baseline: 1.3885x; 1.1861x over previous
//
#include <hip/hip_runtime.h>
#include <math.h>

// Problem constants
#define NB    32
#define NHEAD 16
#define HW    1024
#define SPLIT 8
#define CX    128   // HW / SPLIT

typedef float f32x4  __attribute__((ext_vector_type(4)));
typedef short bf16x4 __attribute__((ext_vector_type(4)));
typedef short bf16x8 __attribute__((ext_vector_type(8)));

__device__ __forceinline__ short f2bf(float f) {   // fp32 -> bf16 RNE
    union { float f; unsigned u; } c; c.f = f;
    unsigned r = c.u + 0x7FFFu + ((c.u >> 16) & 1u);
    return (short)(r >> 16);
}
__device__ __forceinline__ float bf2f(short s) {
    union { unsigned u; float f; } c; c.u = ((unsigned)(unsigned short)s) << 16;
    return c.f;
}
// XOR bank swizzle on byte bits 4..6, keyed by row bits 1..3 (read-optimal).
#define SWZ(row) ((((row) >> 1) & 7) << 4)
#define MFMA16(a, b, c) __builtin_amdgcn_mfma_f32_16x16x32_bf16(a, b, c, 0, 0, 0)

__device__ __forceinline__ bf16x8 lds_ld8(const short* base, int off) {
    return *(const bf16x8*)((const char*)base + off);
}
__device__ __forceinline__ void lds_st4(short* base, int off, bf16x4 v) {
    *(bf16x4*)((char*)base + off) = v;
}

// ---------------------------------------------------------------------------
// Kernel 0: prep — bf16 casts / transposes / bias fold. (unchanged from R3)
// ---------------------------------------------------------------------------
__global__ __launch_bounds__(256) void prep_kernel(
        const float* __restrict__ Wq, const float* __restrict__ token,
        const float* __restrict__ Wk, const float* __restrict__ bq,
        short* __restrict__ Wq_bf, short* __restrict__ tok_t,
        short* __restrict__ Wk_t, float* __restrict__ qkb) {
    __shared__ float red[256];
    const int b = blockIdx.x, t = threadIdx.x;
    if (b < 1024) {
        const size_t idx = (size_t)b * 1024 + t * 4;
        const f32x4 v = *(const f32x4*)(Wq + idx);
        bf16x4 o; o[0]=f2bf(v[0]); o[1]=f2bf(v[1]); o[2]=f2bf(v[2]); o[3]=f2bf(v[3]);
        *(bf16x4*)(Wq_bf + idx) = o;
    } else if (b < 1056) {
        const int n = b - 1024;
        const int c0 = t * 4;
        float arr[4][16];
#pragma unroll
        for (int ci = 0; ci < 4; ++ci)
#pragma unroll
            for (int lq = 0; lq < 4; ++lq) {
                const f32x4 v = *(const f32x4*)(token + (size_t)n*16384 + (size_t)(c0+ci)*16 + lq*4);
#pragma unroll
                for (int e = 0; e < 4; ++e) arr[ci][lq*4+e] = v[e];
            }
#pragma unroll
        for (int l = 0; l < 16; ++l) {
            bf16x4 o; o[0]=f2bf(arr[0][l]); o[1]=f2bf(arr[1][l]); o[2]=f2bf(arr[2][l]); o[3]=f2bf(arr[3][l]);
            *(bf16x4*)(tok_t + (size_t)n*16384 + (size_t)l*1024 + c0) = o;
        }
    } else {
        const int h = b - 1056;
        const int i = t & 63, dq = t >> 6;
        float qs = 0.f; short wt[16];
#pragma unroll
        for (int k = 0; k < 16; ++k) {
            const int d = dq*16 + k;
            const float wv = Wk[(size_t)h*4096 + d*64 + i];
            qs += wv * bq[h*64 + d];
            wt[k] = f2bf(wv);
        }
#pragma unroll
        for (int kq = 0; kq < 4; ++kq) {
            bf16x4 o; o[0]=wt[kq*4]; o[1]=wt[kq*4+1]; o[2]=wt[kq*4+2]; o[3]=wt[kq*4+3];
            *(bf16x4*)(Wk_t + (size_t)h*4096 + i*64 + dq*16 + kq*4) = o;
        }
        red[t] = qs;
        __syncthreads();
        if (t < 64)
            qkb[h*64 + t] = (red[t] + red[t+64] + red[t+128] + red[t+192]) * 0.125f;
    }
}

// ---------------------------------------------------------------------------
// Kernel 1: fused query + qk (all-MFMA). (unchanged from R3)
// ---------------------------------------------------------------------------
__global__ __launch_bounds__(256) void queryqk_kernel(
        const short* __restrict__ Wq_bf, const short* __restrict__ tok_t,
        const short* __restrict__ Wk_t, const float* __restrict__ qkb,
        short* __restrict__ qk_bf) {
    __shared__ short q_ld[16 * 64];   // [l][d] bf16, swizzled
    const int t = threadIdx.x, w = t >> 6, L = t & 63;
    const int lr = L & 15, hg = L >> 4;
    const int nh = blockIdx.x, n = nh >> 4, h = nh & 15;

    f32x4 acc = {0.f, 0.f, 0.f, 0.f};
    const short* aA = Wq_bf + (size_t)(h*64 + w*16 + lr) * 1024 + hg*8;
    const short* aB = tok_t + (size_t)n*16384 + (size_t)lr*1024 + hg*8;
#pragma unroll 4
    for (int ks = 0; ks < 32; ++ks) {
        const bf16x8 a = *(const bf16x8*)(aA + ks*32);
        const bf16x8 bb = *(const bf16x8*)(aB + ks*32);
        acc = MFMA16(a, bb, acc);
    }
    {   // q (no bias) -> q_ld[l][d] bf16; lane holds d = w*16 + hg*4 + r
        bf16x4 qv; qv[0]=f2bf(acc[0]); qv[1]=f2bf(acc[1]); qv[2]=f2bf(acc[2]); qv[3]=f2bf(acc[3]);
        lds_st4(q_ld, (lr*128 + w*32 + hg*8) ^ SWZ(lr), qv);
    }
    __syncthreads();
    f32x4 a2 = {0.f, 0.f, 0.f, 0.f};
#pragma unroll
    for (int ks = 0; ks < 2; ++ks) {
        const bf16x8 a = *(const bf16x8*)(Wk_t + (size_t)h*4096 + (w*16 + lr)*64 + ks*32 + hg*8);
        const bf16x8 bb = lds_ld8(q_ld, (lr*128 + ks*64 + hg*16) ^ SWZ(lr));
        a2 = MFMA16(a, bb, a2);
    }
    const int i0 = w*16 + hg*4;
    bf16x4 qk4;
#pragma unroll
    for (int r = 0; r < 4; ++r)
        qk4[r] = f2bf(a2[r] * 0.125f + qkb[h*64 + i0 + r]);
    *(bf16x4*)(qk_bf + (size_t)nh*1024 + lr*64 + i0) = qk4;
}

// ---------------------------------------------------------------------------
// Kernel 2: attn partial (MFMA). One block per (nh, part); 4 waves.
//   Regular (cached) loads/stores — let L2/L3 absorb both streams.
//   fcp partials stored bf16 lane-major (coalesced 8B/lane).
// ---------------------------------------------------------------------------
__global__ __launch_bounds__(256, 4) void attn_partial(
        const float* __restrict__ feat, const short* __restrict__ qk_bf,
        float* __restrict__ out0, short* __restrict__ fcp_bf,
        float* __restrict__ mz_ws) {
    __shared__ short f_xi[CX * 64];   // [x][i] bf16, 128B rows, swizzled (16 KB)
    __shared__ short f_ix[64 * CX];   // [i][x] bf16, 256B rows, swizzled (16 KB)
    __shared__ short p_ld[16 * CX];   // [l][x] bf16, 256B rows, swizzled (4 KB)
    __shared__ float red_m[64], red_z[64];

    const int t = threadIdx.x, w = t >> 6, L = t & 63;
    const int lr = L & 15, hg = L >> 4;
    const int nh = blockIdx.x, part = blockIdx.y;
    const int n = nh >> 4, h = nh & 15;
    const size_t fbase = (size_t)n*1048576 + (size_t)h*65536 + (size_t)part*CX;

    // ---- stage: x from low bits (coalesced 512B/instr), i from high bits ----
    const int xq = (t & 15) * 4 + ((t >> 4) & 1) * 64;  // x base (0..124)
    const int ib = (t >> 5) * 4;                        // i base within 32-blk
#pragma unroll
    for (int rep = 0; rep < 2; ++rep) {
        const int i0 = ib + 32 * rep;
        f32x4 v[4];
#pragma unroll
        for (int ii = 0; ii < 4; ++ii) {
            const size_t g = fbase + (size_t)(i0+ii)*1024 + xq;
            v[ii] = *(const f32x4*)(feat + g);
            *(f32x4*)(out0 + g) = v[ii];                 // passthrough copy
        }
#pragma unroll
        for (int ii = 0; ii < 4; ++ii) {   // f_ix[i][x]: 4 consecutive x
            bf16x4 bv; bv[0]=f2bf(v[ii][0]); bv[1]=f2bf(v[ii][1]); bv[2]=f2bf(v[ii][2]); bv[3]=f2bf(v[ii][3]);
            lds_st4(f_ix, ((i0+ii)*256 + xq*2) ^ SWZ(i0+ii), bv);
        }
#pragma unroll
        for (int j = 0; j < 4; ++j) {      // f_xi[x][i]: 4 consecutive i
            bf16x4 bv; bv[0]=f2bf(v[0][j]); bv[1]=f2bf(v[1][j]); bv[2]=f2bf(v[2][j]); bv[3]=f2bf(v[3][j]);
            lds_st4(f_xi, ((xq+j)*128 + i0*2) ^ SWZ(xq+j), bv);
        }
    }
    // qk B-fragments straight from global (L2-hot, 2 x b128)
    const bf16x8 qb0 = *(const bf16x8*)(qk_bf + (size_t)nh*1024 + lr*64 + hg*8);
    const bf16x8 qb1 = *(const bf16x8*)(qk_bf + (size_t)nh*1024 + lr*64 + 32 + hg*8);
    __syncthreads();

    // ---- logits: wave w owns x-tiles 2w, 2w+1 ----
    f32x4 s0 = {0.f,0.f,0.f,0.f}, s1 = {0.f,0.f,0.f,0.f};
    {
        const int x0r = (2*w)*16 + lr, x1r = (2*w+1)*16 + lr;
        bf16x8 a;
        a = lds_ld8(f_xi, (x0r*128      + hg*16) ^ SWZ(x0r)); s0 = MFMA16(a, qb0, s0);
        a = lds_ld8(f_xi, (x0r*128 + 64 + hg*16) ^ SWZ(x0r)); s0 = MFMA16(a, qb1, s0);
        a = lds_ld8(f_xi, (x1r*128      + hg*16) ^ SWZ(x1r)); s1 = MFMA16(a, qb0, s1);
        a = lds_ld8(f_xi, (x1r*128 + 64 + hg*16) ^ SWZ(x1r)); s1 = MFMA16(a, qb1, s1);
    }
    // ---- softmax over this part's 128 x, per l ----
    float ml = fmaxf(fmaxf(fmaxf(s0[0],s0[1]), fmaxf(s0[2],s0[3])),
                     fmaxf(fmaxf(s1[0],s1[1]), fmaxf(s1[2],s1[3])));
    ml = fmaxf(ml, __shfl_xor(ml, 16));
    ml = fmaxf(ml, __shfl_xor(ml, 32));
    if (L < 16) red_m[w*16 + L] = ml;
    __syncthreads();
    const float m = fmaxf(fmaxf(red_m[lr], red_m[16+lr]),
                          fmaxf(red_m[32+lr], red_m[48+lr]));
    float p0[4], p1[4]; float zs = 0.f;
#pragma unroll
    for (int r = 0; r < 4; ++r) {
        p0[r] = __expf(s0[r] - m); p1[r] = __expf(s1[r] - m);
        zs += p0[r] + p1[r];
    }
    {   // P -> p_ld[l][x]
        bf16x4 b0; b0[0]=f2bf(p0[0]); b0[1]=f2bf(p0[1]); b0[2]=f2bf(p0[2]); b0[3]=f2bf(p0[3]);
        bf16x4 b1; b1[0]=f2bf(p1[0]); b1[1]=f2bf(p1[1]); b1[2]=f2bf(p1[2]); b1[3]=f2bf(p1[3]);
        lds_st4(p_ld, (lr*256 + (2*w)*32   + hg*8) ^ SWZ(lr), b0);
        lds_st4(p_ld, (lr*256 + (2*w+1)*32 + hg*8) ^ SWZ(lr), b1);
    }
    zs += __shfl_xor(zs, 16);
    zs += __shfl_xor(zs, 32);
    if (L < 16) red_z[w*16 + L] = zs;
    __syncthreads();

    // ---- fc = f_ix @ P : wave w owns i-tile w, K = 128 x ----
    f32x4 fa = {0.f,0.f,0.f,0.f};
    const int ir = w*16 + lr;
#pragma unroll
    for (int ks = 0; ks < 4; ++ks) {
        const bf16x8 a  = lds_ld8(f_ix, (ir*256 + ks*64 + hg*16) ^ SWZ(ir));
        const bf16x8 bb = lds_ld8(p_ld, (lr*256 + ks*64 + hg*16) ^ SWZ(lr));
        fa = MFMA16(a, bb, fa);
    }
    {   // lane-major bf16 store: element r is (i = w*16+hg*4+r, l = lr)
        bf16x4 fb; fb[0]=f2bf(fa[0]); fb[1]=f2bf(fa[1]); fb[2]=f2bf(fa[2]); fb[3]=f2bf(fa[3]);
        *(bf16x4*)(fcp_bf + ((size_t)nh*SPLIT + part)*1024 + t*4) = fb;
    }
    if (w == 0 && L < 16) {
        const float Z = red_z[L] + red_z[16+L] + red_z[32+L] + red_z[48+L];
        mz_ws[((size_t)nh*SPLIT + part)*32 + L]      = m;
        mz_ws[((size_t)nh*SPLIT + part)*32 + 16 + L] = Z;
    }
}

// ---------------------------------------------------------------------------
// Kernel 3: combine partials + Wv epilogue. grid 512.
//   fcp is bf16 lane-major: thread t's element r = (i = (t>>6)*16+((t>>4)&3)*4+r,
//   l = t&15).  Regular cached loads (fcp/mz are L2-resident).
// ---------------------------------------------------------------------------
__global__ __launch_bounds__(256) void attn_combine(
        const short* __restrict__ fcp_bf, const float* __restrict__ mz_ws,
        const float* __restrict__ Wv, const float* __restrict__ bv,
        float* __restrict__ out1) {
    __shared__ float wv_lds[64 * 65];
    __shared__ float s_lds[64 * 20];
    __shared__ float mz_lds[SPLIT * 32];

    const int t  = threadIdx.x;
    const int nh = blockIdx.x;
    const int n  = nh >> 4, h = nh & 15;

    mz_lds[t] = mz_ws[(size_t)nh * SPLIT * 32 + t];
#pragma unroll
    for (int k = 0; k < 4; ++k) {   // stage Wv transposed: wv_lds[i][d]
        const int flat = t + 256 * k;
        const int d = flat >> 4, i4 = (flat & 15) * 4;
        const f32x4 v = *(const f32x4*)(Wv + (size_t)h * 4096 + d * 64 + i4);
        wv_lds[(i4 + 0) * 65 + d] = v[0];
        wv_lds[(i4 + 1) * 65 + d] = v[1];
        wv_lds[(i4 + 2) * 65 + d] = v[2];
        wv_lds[(i4 + 3) * 65 + d] = v[3];
    }
    __syncthreads();

    {   // combine: this thread owns 4 i-values at one l
        const int l = t & 15, i0d = (t >> 6) * 16 + ((t >> 4) & 3) * 4;
        float m = -INFINITY;
#pragma unroll
        for (int pp = 0; pp < SPLIT; ++pp) m = fmaxf(m, mz_lds[pp * 32 + l]);
        float Z = 0.f, a0 = 0.f, a1 = 0.f, a2 = 0.f, a3 = 0.f;
#pragma unroll
        for (int pp = 0; pp < SPLIT; ++pp) {
            const float wgt = __expf(mz_lds[pp * 32 + l] - m);
            Z += wgt * mz_lds[pp * 32 + 16 + l];
            const bf16x4 fv = *(const bf16x4*)(fcp_bf + ((size_t)nh * SPLIT + pp) * 1024 + t * 4);
            a0 += wgt * bf2f(fv[0]); a1 += wgt * bf2f(fv[1]);
            a2 += wgt * bf2f(fv[2]); a3 += wgt * bf2f(fv[3]);
        }
        const float rz = 1.f / Z;
        s_lds[(i0d + 0) * 20 + l] = a0 * rz;
        s_lds[(i0d + 1) * 20 + l] = a1 * rz;
        s_lds[(i0d + 2) * 20 + l] = a2 * rz;
        s_lds[(i0d + 3) * 20 + l] = a3 * rz;
    }
    __syncthreads();
    {   // tok[d][l] = sum_i Wv[d][i] * fcn[i][l] + bv
        const int d = t & 63, lq = t >> 6;
        float a0 = 0.f, a1 = 0.f, a2 = 0.f, a3 = 0.f;
#pragma unroll 8
        for (int ii = 0; ii < 64; ++ii) {
            const float wv = wv_lds[ii * 65 + d];
            const f32x4 f4 = *(const f32x4*)(s_lds + ii * 20 + lq * 4);
            a0 += wv * f4[0]; a1 += wv * f4[1]; a2 += wv * f4[2]; a3 += wv * f4[3];
        }
        const float b = bv[h * 64 + d];
        f32x4 r = {a0 + b, a1 + b, a2 + b, a3 + b};
        *(f32x4*)(out1 + (size_t)n * 16384 + (size_t)(h * 64 + d) * 16 + lq * 4) = r;
    }
}

// ---------------------------------------------------------------------------
extern "C" void kernel_launch(void* const* d_in, const int* in_sizes, int n_in,
                              void* d_out, int out_size, void* d_ws, size_t ws_size,
                              hipStream_t stream) {
    const float* feature = (const float*)d_in[0];
    const float* token   = (const float*)d_in[1];
    const float* Wq      = (const float*)d_in[2];
    const float* bq      = (const float*)d_in[3];
    const float* Wk      = (const float*)d_in[4];
    // d_in[5] = bk: provably unused (constant along softmax axis)
    const float* Wv      = (const float*)d_in[6];
    const float* bv      = (const float*)d_in[7];

    float* out0 = (float*)d_out;                      // feature passthrough
    float* out1 = out0 + (size_t)NB * 1024 * HW;      // tok [n][c][l]

    short* Wq_bf  = (short*)d_ws;                               // 2 MB
    short* tok_t  = Wq_bf + (size_t)1024 * 1024;                // 1 MB
    short* Wk_t   = tok_t + (size_t)NB * 16 * 1024;             // 128 KB
    short* qk_bf  = Wk_t + (size_t)NHEAD * 64 * 64;             // 1 MB
    float* qkb    = (float*)(qk_bf + (size_t)NB * NHEAD * 1024);// 4 KB
    short* fcp_bf = (short*)(qkb + NHEAD * 64);                 // 8 MB
    float* mz     = (float*)(fcp_bf + (size_t)NB * NHEAD * SPLIT * 1024); // 0.5 MB

    prep_kernel   <<<dim3(1072), 256, 0, stream>>>(Wq, token, Wk, bq, Wq_bf, tok_t, Wk_t, qkb);
    queryqk_kernel<<<dim3(NB * NHEAD), 256, 0, stream>>>(Wq_bf, tok_t, Wk_t, qkb, qk_bf);
    attn_partial  <<<dim3(NB * NHEAD, SPLIT), 256, 0, stream>>>(feature, qk_bf, out0, fcp_bf, mz);
    attn_combine  <<<dim3(NB * NHEAD), 256, 0, stream>>>(fcp_bf, mz, Wv, bv, out1);
}